// Round 6
// baseline (357.442 us; speedup 1.0000x reference)
//
#include <hip/hip_runtime.h>

#define LOG2E 1.442695040888963f

typedef float f32x2 __attribute__((ext_vector_type(2)));

// v_pk_fma_f32 / v_pk_mul_f32 with a wave-uniform SGPR-pair as src0
// (h values broadcast via v_readlane -> SGPRs; VOP3P allows 1 scalar src).
static __device__ __forceinline__ void pkfma_sv(f32x2& acc, long h, f32x2 w) {
    asm("v_pk_fma_f32 %0, %1, %2, %0" : "+v"(acc) : "s"(h), "v"(w));
}
static __device__ __forceinline__ void pkmul_sv(f32x2& d, long h, f32x2 w) {
    asm("v_pk_mul_f32 %0, %1, %2" : "=v"(d) : "s"(h), "v"(w));
}

// One batch element per 64-lane wave (2048 blocks, 2 waves/SIMD).
// Rows 0..103 = gates i,f,g,o. Lane l<52 owns row l (dot0) and row l+52 (dot1):
//   l<26:        dot0 = i_l (sigmoid), dot1 = g_l (tanh)
//   l in[26,52): dot0 = f_{l-26} (sigmoid), dot1 = o_{l-26} (sigmoid)
// Cell state c_j lives in lane 26+j: only i*g crosses lanes (one ds_bpermute).
// h transport: 26 v_readlane -> 13 SGPR pairs feeding v_pk_fma src0 directly.
// No LDS h round-trip, no barriers in the T-loop, epilogue needs no LDS.
// P and W_hh prescaled by the exp2 multipliers (-log2e / -2log2e), fp32.
__launch_bounds__(64, 2)
__global__ void lstm_char_kernel(const int* __restrict__ x,      // [B,T] int32
                                 const float* __restrict__ E,     // [26,26]
                                 const float* __restrict__ W_ih,  // [104,26]
                                 const float* __restrict__ W_hh,  // [104,26]
                                 const float* __restrict__ b_ih,  // [104]
                                 const float* __restrict__ b_hh,  // [104]
                                 const float* __restrict__ W_lin, // [26,26]
                                 const float* __restrict__ b_lin, // [26]
                                 float* __restrict__ out,         // [B,26]
                                 int T)
{
    constexpr int H = 26;

    __shared__ __align__(16) f32x2 P[27][52];   // prescaled, pair-interleaved
    __shared__ float Ebuf[676];
    __shared__ int   chars[1026];               // premultiplied byte offsets

    const int b = blockIdx.x;
    const int l = threadIdx.x;
    const bool act = (l < 52);
    const int r0 = act ? l : 0;
    const int r1 = act ? l + 52 : 0;

    // ---- stage E, char sequence (as P-row byte offsets: 52 pairs * 8 B) ----
    for (int i = l; i < 676; i += 64) Ebuf[i] = E[i];
    for (int t = l; t < T; t += 64) chars[t] = x[(size_t)b * T + t] * 416;
    if (l < 2) chars[1024 + l] = 0;

    // per-lane exp2 prescale: dot0 (i or f) sigmoid; dot1 tanh (l<26) else sigmoid
    const float m0 = -LOG2E;
    const float m1 = (l < 26) ? (-2.0f * LOG2E) : (-LOG2E);
    const float s1 = (l < 26) ? 2.0f : 1.0f;
    const float d1 = (l < 26) ? -1.0f : 0.0f;

    // ---- prescaled fp32 recurrent weights as packed pairs ----
    f32x2 wh0p[13], wh1p[13];
    #pragma unroll
    for (int k = 0; k < 13; ++k) {
        wh0p[k] = f32x2{W_hh[r0 * H + 2 * k] * m0, W_hh[r0 * H + 2 * k + 1] * m0};
        wh1p[k] = f32x2{W_hh[r1 * H + 2 * k] * m1, W_hh[r1 * H + 2 * k + 1] * m1};
    }

    // ---- build prescaled pair-interleaved P table ----
    {
        float wi0[H], wi1[H];
        #pragma unroll
        for (int k = 0; k < H; ++k) {
            wi0[k] = W_ih[r0 * H + k];
            wi1[k] = W_ih[r1 * H + k];
        }
        const float bias0 = b_ih[r0] + b_hh[r0];
        const float bias1 = b_ih[r1] + b_hh[r1];
        __syncthreads();
        for (int ch = 0; ch < 26; ++ch) {
            float a0 = bias0, a1 = bias1;
            #pragma unroll
            for (int k = 0; k < H; ++k) {
                float e = Ebuf[ch * H + k];
                a0 = fmaf(wi0[k], e, a0);
                a1 = fmaf(wi1[k], e, a1);
            }
            if (act) P[ch][l] = f32x2{a0 * m0, a1 * m1};
        }
    }
    __syncthreads();

    const int bpaddr = ((l - 26) & 63) << 2;   // lane l pulls from lane l-26
    const char* Pb = (const char*)&P[0][0];
    const int lane8 = l << 3;

    // ---- pipeline prologue: h = 0 -> all SGPR h-pairs zero ----
    long hp[13];
    #pragma unroll
    for (int q = 0; q < 13; ++q) hp[q] = 0;

    int poffn = chars[1];
    f32x2 pa = *(const f32x2*)(Pb + chars[0] + lane8);
    float c = 0.0f;

    #pragma unroll 2
    for (int t = 0; t < T; ++t) {
        // prefetch P pair for t+1, char offset for t+2 (independent)
        f32x2 pn = *(const f32x2*)(Pb + poffn + lane8);
        int poff2 = chars[t + 2];

        // two dot products; h comes from SGPR pairs (no LDS, no stall)
        f32x2 A0, A1, B0, B1;
        pkmul_sv(A0, hp[0], wh0p[0]);
        pkmul_sv(A1, hp[1], wh0p[1]);
        pkmul_sv(B0, hp[0], wh1p[0]);
        pkmul_sv(B1, hp[1], wh1p[1]);
        #pragma unroll
        for (int k = 2; k < 12; k += 2) {
            pkfma_sv(A0, hp[k],     wh0p[k]);
            pkfma_sv(A1, hp[k + 1], wh0p[k + 1]);
            pkfma_sv(B0, hp[k],     wh1p[k]);
            pkfma_sv(B1, hp[k + 1], wh1p[k + 1]);
        }
        pkfma_sv(A0, hp[12], wh0p[12]);
        pkfma_sv(B0, hp[12], wh1p[12]);
        f32x2 sa = A0 + A1;
        f32x2 sb = B0 + B1;
        const float a0s = sa.x + sa.y + pa.x;   // prescaled for exp2
        const float a1s = sb.x + sb.y + pa.y;

        // activations
        float y0 = __builtin_amdgcn_rcpf(1.0f + __builtin_amdgcn_exp2f(a0s));
        float y1 = fmaf(__builtin_amdgcn_rcpf(1.0f + __builtin_amdgcn_exp2f(a1s)),
                        s1, d1);

        // i*g crosses lanes: lane 26+j pulls y0*y1 from lane j
        float pr = y0 * y1;
        float pp = __int_as_float(
            __builtin_amdgcn_ds_bpermute(bpaddr, __float_as_int(pr)));

        // c,h update (lane-local in lanes 26..51; junk elsewhere)
        c = fmaf(y0, c, pp);
        float th = fmaf(__builtin_amdgcn_rcpf(
                            1.0f + __builtin_amdgcn_exp2f(c * (-2.0f * LOG2E))),
                        2.0f, -1.0f);
        float hv = y1 * th;

        // broadcast h: 26 readlanes -> 13 SGPR pairs (SALU packing, free pipe)
        const int hb = __float_as_int(hv);
        #pragma unroll
        for (int q = 0; q < 13; ++q) {
            unsigned lo = (unsigned)__builtin_amdgcn_readlane(hb, 26 + 2 * q);
            unsigned hi = (unsigned)__builtin_amdgcn_readlane(hb, 26 + 2 * q + 1);
            hp[q] = (long)(((unsigned long long)hi << 32) | lo);
        }

        pa = pn; poffn = poff2;
    }

    // ---- final linear: every lane holds all h in SGPRs -> no LDS needed ----
    if (l < H) {
        float acc = b_lin[l];
        #pragma unroll
        for (int q = 0; q < 13; ++q) {
            float h0 = __int_as_float((int)(unsigned)hp[q]);
            float h1 = __int_as_float((int)(unsigned)((unsigned long long)hp[q] >> 32));
            acc = fmaf(W_lin[l * H + 2 * q],     h0, acc);
            acc = fmaf(W_lin[l * H + 2 * q + 1], h1, acc);
        }
        out[(size_t)b * H + l] = acc;
    }
}

extern "C" void kernel_launch(void* const* d_in, const int* in_sizes, int n_in,
                              void* d_out, int out_size, void* d_ws, size_t ws_size,
                              hipStream_t stream) {
    const int*   x     = (const int*)d_in[0];
    const float* E     = (const float*)d_in[1];
    const float* W_ih  = (const float*)d_in[2];
    const float* W_hh  = (const float*)d_in[3];
    const float* b_ih  = (const float*)d_in[4];
    const float* b_hh  = (const float*)d_in[5];
    const float* W_lin = (const float*)d_in[6];
    const float* b_lin = (const float*)d_in[7];
    float* out = (float*)d_out;

    const int T = 1024;
    const int B = in_sizes[0] / T;   // 2048

    lstm_char_kernel<<<B, 64, 0, stream>>>(x, E, W_ih, W_hh, b_ih, b_hh,
                                           W_lin, b_lin, out, T);
}

// Round 11
// 285.071 us; speedup vs baseline: 1.2539x; 1.2539x over previous
//
#include <hip/hip_runtime.h>

#define LOG2E 1.442695040888963f

typedef float f32x2 __attribute__((ext_vector_type(2)));
typedef float f32x4 __attribute__((ext_vector_type(4)));

// packed fp32 FMA / MUL (VOP3P; half-rate on gfx950 but halves instruction count)
static __device__ __forceinline__ void pkfma(f32x2& acc, f32x2 a, f32x2 b) {
    asm("v_pk_fma_f32 %0, %1, %2, %0" : "+v"(acc) : "v"(a), "v"(b));
}
static __device__ __forceinline__ void pkmul(f32x2& d, f32x2 a, f32x2 b) {
    asm("v_pk_mul_f32 %0, %1, %2" : "=v"(d) : "v"(a), "v"(b));
}

// One batch element per 64-lane wave (2048 blocks, 2 waves/SIMD).
// Gate rows 0..103 = i,f,g,o. Lane mapping (j = l & 31, rows clamped for j>=26):
//   lanes  0..25: dot0 = i_j (sigmoid), dot1 = g_j (scaled tanh)
//   lanes 32..57: dot0 = f_j (sigmoid), dot1 = o_j (sigmoid)
//
// Cross-lane move (scaled i*g -> c-lane), SEMANTICS-PROOF form:
//   sw = permlane32_swap(pr, pr); rcv = sw[0] + sw[1] - pr.
//   Evidence: R7/R8/R9 (coalescible operands) kept the local value at high
//   lanes (absmax 0.6016 x3); R10 (swap(pr,0), consumed sw[1]) delivered 0
//   (absmax 0.455 = b_lin-only output) => exchange is vdst_high<->vsrc_low.
//   Using BOTH outputs: exactly one holds the remote pr[j], the other the
//   local product, under EITHER direction convention -> sum minus local is
//   the remote value. Both defs live simultaneously => allocator cannot
//   merge vdst/vsrc => no same-register degenerate.
//
// Cell state tracked as C' = -2*log2e*c  =>  tanh(c) needs no mul before exp2:
//   C' = sig(f)*C' + y0*y1   with  y1(g-lane) = -4log2e*sig(2g) + 2log2e
//   h  = sig(o)*tanh(c) = fma(rcp(1+exp2(C')), 2*sig(o), -sig(o))
// P and W_hh prescaled by the exp2 multipliers; h broadcast via 7 uniform
// ds_read_b128. Single-wave workgroup => no barriers in the T-loop.
__launch_bounds__(64, 2)
__global__ void lstm_char_kernel(const int* __restrict__ x,      // [B,T] int32
                                 const float* __restrict__ E,     // [26,26]
                                 const float* __restrict__ W_ih,  // [104,26]
                                 const float* __restrict__ W_hh,  // [104,26]
                                 const float* __restrict__ b_ih,  // [104]
                                 const float* __restrict__ b_hh,  // [104]
                                 const float* __restrict__ W_lin, // [26,26]
                                 const float* __restrict__ b_lin, // [26]
                                 float* __restrict__ out,         // [B,26]
                                 int T)
{
    constexpr int H = 26;

    __shared__ __align__(16) f32x2 P[26][64];   // prescaled, pair-interleaved, per-lane
    __shared__ float Ebuf[676];
    __shared__ int   chars[1026];               // premultiplied byte offsets (x * 512)
    __shared__ __align__(16) float hbuf[64];

    const int b = blockIdx.x;
    const int l = threadIdx.x;
    const int j = l & 31;
    const bool lo = (l < 32);
    const int rr = (j < 26) ? j : 0;            // clamp inactive lanes to row 0
    const int r0 = lo ? rr : 26 + rr;           // i or f row
    const int r1 = lo ? 52 + rr : 78 + rr;      // g or o row

    // ---- stage E, char sequence (P-row byte offsets: 64 pairs * 8 B = 512) ----
    for (int i = l; i < 676; i += 64) Ebuf[i] = E[i];
    for (int t = l; t < T; t += 64) chars[t] = x[(size_t)b * T + t] * 512;
    if (l < 2) chars[1024 + l] = 0;
    hbuf[l] = 0.0f;

    // exp2 prescales: dot0 (i or f) sigmoid; dot1 scaled-tanh (g) or sigmoid (o)
    const float m0 = -LOG2E;
    const float m1 = lo ? (-2.0f * LOG2E) : (-LOG2E);
    const float s1 = lo ? (-4.0f * LOG2E) : 1.0f;   // y1 = fma(rcp, s1, d1)
    const float d1 = lo ? ( 2.0f * LOG2E) : 0.0f;

    // ---- prescaled fp32 recurrent weights as packed pairs ----
    f32x2 wh0p[13], wh1p[13];
    #pragma unroll
    for (int k = 0; k < 13; ++k) {
        wh0p[k] = f32x2{W_hh[r0 * H + 2 * k] * m0, W_hh[r0 * H + 2 * k + 1] * m0};
        wh1p[k] = f32x2{W_hh[r1 * H + 2 * k] * m1, W_hh[r1 * H + 2 * k + 1] * m1};
    }

    // ---- build prescaled pair-interleaved P table (all 64 lane slots) ----
    {
        float wi0[H], wi1[H];
        #pragma unroll
        for (int k = 0; k < H; ++k) {
            wi0[k] = W_ih[r0 * H + k];
            wi1[k] = W_ih[r1 * H + k];
        }
        const float bias0 = b_ih[r0] + b_hh[r0];
        const float bias1 = b_ih[r1] + b_hh[r1];
        __syncthreads();
        for (int ch = 0; ch < 26; ++ch) {
            float a0 = bias0, a1 = bias1;
            #pragma unroll
            for (int k = 0; k < H; ++k) {
                float e = Ebuf[ch * H + k];
                a0 = fmaf(wi0[k], e, a0);
                a1 = fmaf(wi1[k], e, a1);
            }
            P[ch][l] = f32x2{a0 * m0, a1 * m1};
        }
    }
    __syncthreads();

    const int hidx = (l - 32) & 63;   // 32..57 -> 0..25 (real h); others -> junk zone
    const char* Pb = (const char*)&P[0][0];
    const int lane8 = l << 3;

    // ---- pipeline prologue ----
    int poffn = chars[1];
    f32x2 pa = *(const f32x2*)(Pb + chars[0] + lane8);
    float C = 0.0f;                   // C' = -2*log2e*c, lives in lanes 32..57

    #pragma unroll 2
    for (int t = 0; t < T; ++t) {
        // h broadcast FIRST (7 uniform-address b128 reads -> 13 packed pairs)
        f32x4 hv4[7];
        #pragma unroll
        for (int q = 0; q < 7; ++q) hv4[q] = ((const f32x4*)hbuf)[q];
        f32x2 hp[13];
        #pragma unroll
        for (int q = 0; q < 6; ++q) {
            hp[2 * q]     = f32x2{hv4[q].x, hv4[q].y};
            hp[2 * q + 1] = f32x2{hv4[q].z, hv4[q].w};
        }
        hp[12] = f32x2{hv4[6].x, hv4[6].y};

        // prefetch P pair for t+1, char offset for t+2 (off critical path)
        f32x2 pn = *(const f32x2*)(Pb + poffn + lane8);
        int poff2 = chars[t + 2];

        // two dot products, 2 packed accumulator chains each
        f32x2 A0, A1, B0, B1;
        pkmul(A0, hp[0], wh0p[0]);
        pkmul(A1, hp[1], wh0p[1]);
        pkmul(B0, hp[0], wh1p[0]);
        pkmul(B1, hp[1], wh1p[1]);
        #pragma unroll
        for (int k = 2; k < 12; k += 2) {
            pkfma(A0, hp[k],     wh0p[k]);
            pkfma(A1, hp[k + 1], wh0p[k + 1]);
            pkfma(B0, hp[k],     wh1p[k]);
            pkfma(B1, hp[k + 1], wh1p[k + 1]);
        }
        pkfma(A0, hp[12], wh0p[12]);
        pkfma(B0, hp[12], wh1p[12]);
        f32x2 sa = A0 + A1;
        f32x2 sb = B0 + B1;
        const float a0s = sa.x + sa.y + pa.x;   // prescaled for exp2
        const float a1s = sb.x + sb.y + pa.y;

        // activations
        float y0 = __builtin_amdgcn_rcpf(1.0f + __builtin_amdgcn_exp2f(a0s));
        float y1 = fmaf(__builtin_amdgcn_rcpf(1.0f + __builtin_amdgcn_exp2f(a1s)),
                        s1, d1);
        float y1_2 = y1 + y1;                   // off-chain helpers for h = o*tanh(c)
        float ny1  = -y1;

        // cross-lane: lanes 32..57 receive scaled i*g from lanes 0..25.
        // Direction-agnostic: one of sw[0]/sw[1] is the remote value, the
        // other is the local product; sum - local = remote either way.
        float pr = y0 * y1;                      // i * (-2log2e * tanh g) in lanes<26
        auto sw = __builtin_amdgcn_permlane32_swap(__float_as_int(pr),
                                                   __float_as_int(pr),
                                                   false, false);
        float rcv = (__int_as_float(sw[0]) + __int_as_float(sw[1])) - pr;

        // C', h update (meaningful in lanes 32..57)
        C = fmaf(y0, C, rcv);                    // sig(f)*C' + (-2log2e)*i*g
        float rc = __builtin_amdgcn_rcpf(1.0f + __builtin_amdgcn_exp2f(C));
        float hv = fmaf(rc, y1_2, ny1);          // sig(o)*tanh(c)
        hbuf[hidx] = hv;

        pa = pn; poffn = poff2;
    }

    __syncthreads();

    // ---- final linear: out[b, j] = W_lin[j]·h + b_lin[j] ----
    if (l < H) {
        float acc = b_lin[l];
        #pragma unroll
        for (int k = 0; k < H; ++k)
            acc = fmaf(W_lin[l * H + k], hbuf[k], acc);
        out[(size_t)b * H + l] = acc;
    }
}

extern "C" void kernel_launch(void* const* d_in, const int* in_sizes, int n_in,
                              void* d_out, int out_size, void* d_ws, size_t ws_size,
                              hipStream_t stream) {
    const int*   x     = (const int*)d_in[0];
    const float* E     = (const float*)d_in[1];
    const float* W_ih  = (const float*)d_in[2];
    const float* W_hh  = (const float*)d_in[3];
    const float* b_ih  = (const float*)d_in[4];
    const float* b_hh  = (const float*)d_in[5];
    const float* W_lin = (const float*)d_in[6];
    const float* b_lin = (const float*)d_in[7];
    float* out = (float*)d_out;

    const int T = 1024;
    const int B = in_sizes[0] / T;   // 2048

    lstm_char_kernel<<<B, 64, 0, stream>>>(x, E, W_ih, W_hh, b_ih, b_hh,
                                           W_lin, b_lin, out, T);
}

// Round 12
// 276.308 us; speedup vs baseline: 1.2936x; 1.0317x over previous
//
#include <hip/hip_runtime.h>

#define LOG2E 1.442695040888963f

typedef float f32x2 __attribute__((ext_vector_type(2)));

// packed fp32 FMA / MUL (VOP3P; half-rate on gfx950 but halves instruction count)
static __device__ __forceinline__ void pkfma(f32x2& acc, f32x2 a, f32x2 b) {
    asm("v_pk_fma_f32 %0, %1, %2, %0" : "+v"(acc) : "v"(a), "v"(b));
}
static __device__ __forceinline__ void pkmul(f32x2& d, f32x2 a, f32x2 b) {
    asm("v_pk_mul_f32 %0, %1, %2" : "=v"(d) : "v"(a), "v"(b));
}

// One batch element per 64-lane wave (2048 blocks; LDS <=16KB so 8 blocks/CU
// = full 2 waves/SIMD, vs 7 at R11's 20.5KB).
// Gate rows 0..103 = i,f,g,o. Lane mapping (j = l & 31, rows clamped j>=26):
//   lanes  0..25: dot0 = i_j (sigmoid), dot1 = g_j (scaled tanh)
//   lanes 32..57: dot0 = f_j (sigmoid), dot1 = o_j (sigmoid)
// Cross-lane (scaled i*g -> c-lane): permlane32_swap with PROVEN semantics
// (R10 zeros + R11 pass): sw[0][32+j] = vsrc_old[j]. Use swap(y0, pr) ->
// rcv = sw[0]; y0 is live after (C fma) so vdst/vsrc cannot coalesce.
// Cell state tracked as C' = -2*log2e*c; h = fma(rcp(1+exp2(C')), 2*sig(o), -sig(o)).
// ANTI-PHASE SKEW: co-resident waves run identical code and phase-lock,
// stalling on the h LDS round-trip simultaneously (R11: wall 787cy/step-pair
// = 2x per-wave chain, VALUBusy 70%). A hash-of-blockIdx prologue delay
// (0..7 x ~4 dependent v_rcp) offsets them so one wave's stall hides under
// the other's issue.
__launch_bounds__(64, 2)
__global__ void lstm_char_kernel(const int* __restrict__ x,      // [B,T] int32
                                 const float* __restrict__ E,     // [26,26]
                                 const float* __restrict__ W_ih,  // [104,26]
                                 const float* __restrict__ W_hh,  // [104,26]
                                 const float* __restrict__ b_ih,  // [104]
                                 const float* __restrict__ b_hh,  // [104]
                                 const float* __restrict__ W_lin, // [26,26]
                                 const float* __restrict__ b_lin, // [26]
                                 float* __restrict__ out,         // [B,26]
                                 int T)
{
    constexpr int H = 26;

    __shared__ __align__(16) f32x2 P[26][64];          // 13312 B, pair-interleaved
    __shared__ __align__(8) unsigned short chars[1032]; // 2064 B, premultiplied offs
    __shared__ __align__(16) float hbuf[64];            // 256 B

    const int b = blockIdx.x;
    const int l = threadIdx.x;
    const int j = l & 31;
    const bool lo = (l < 32);
    const int rr = (j < 26) ? j : 0;            // clamp inactive lanes to row 0
    const int r0 = lo ? rr : 26 + rr;           // i or f row
    const int r1 = lo ? 52 + rr : 78 + rr;      // g or o row

    // ---- stage char sequence as u16 P-row byte offsets (64 pairs * 8 = 512) ----
    for (int t = l; t < T; t += 64)
        chars[t] = (unsigned short)(x[(size_t)b * T + t] * 512);
    if (l < 8) chars[1024 + l] = 0;
    hbuf[l] = 0.0f;

    // exp2 prescales: dot0 (i or f) sigmoid; dot1 scaled-tanh (g) or sigmoid (o)
    const float m0 = -LOG2E;
    const float m1 = lo ? (-2.0f * LOG2E) : (-LOG2E);
    const float s1 = lo ? (-4.0f * LOG2E) : 1.0f;   // y1 = fma(rcp, s1, d1)
    const float d1 = lo ? ( 2.0f * LOG2E) : 0.0f;

    // ---- prescaled fp32 recurrent weights as packed pairs ----
    f32x2 wh0p[13], wh1p[13];
    #pragma unroll
    for (int k = 0; k < 13; ++k) {
        wh0p[k] = f32x2{W_hh[r0 * H + 2 * k] * m0, W_hh[r0 * H + 2 * k + 1] * m0};
        wh1p[k] = f32x2{W_hh[r1 * H + 2 * k] * m1, W_hh[r1 * H + 2 * k + 1] * m1};
    }

    // ---- build prescaled pair-interleaved P table (E read direct: uniform
    //      s_loads, prologue-only; no Ebuf staging => LDS diet) ----
    {
        float wi0[H], wi1[H];
        #pragma unroll
        for (int k = 0; k < H; ++k) {
            wi0[k] = W_ih[r0 * H + k];
            wi1[k] = W_ih[r1 * H + k];
        }
        const float bias0 = b_ih[r0] + b_hh[r0];
        const float bias1 = b_ih[r1] + b_hh[r1];
        for (int ch = 0; ch < 26; ++ch) {
            float a0 = bias0, a1 = bias1;
            #pragma unroll
            for (int k = 0; k < H; ++k) {
                float e = E[ch * H + k];
                a0 = fmaf(wi0[k], e, a0);
                a1 = fmaf(wi1[k], e, a1);
            }
            P[ch][l] = f32x2{a0 * m0, a1 * m1};
        }
    }
    __syncthreads();

    // ---- anti-phase skew: 0..7 units of 4 dependent v_rcp (~50cy each) ----
    {
        unsigned hsh = (blockIdx.x * 2654435761u) >> 29;   // top 3 hash bits
        float dch = (float)(l + 1);
        for (unsigned i = 0; i < hsh; ++i) {
            asm volatile("v_rcp_f32 %0, %0\n\t"
                         "v_rcp_f32 %0, %0\n\t"
                         "v_rcp_f32 %0, %0\n\t"
                         "v_rcp_f32 %0, %0" : "+v"(dch));
        }
        asm volatile("" :: "v"(dch));   // keep the chain live
    }

    const int hidx = (l - 32) & 63;   // 32..57 -> 0..25 (real h); others -> junk zone
    const char* Pb = (const char*)&P[0][0];
    const int lane8 = l << 3;

    // ---- pipeline prologue ----
    int poffn = chars[1];
    f32x2 pa = *(const f32x2*)(Pb + (int)chars[0] + lane8);
    float C = 0.0f;                   // C' = -2*log2e*c, lives in lanes 32..57

    #pragma unroll 2
    for (int t = 0; t < T; ++t) {
        // h broadcast: 13 uniform-address b64 reads straight into pairs
        f32x2 hp[13];
        #pragma unroll
        for (int q = 0; q < 13; ++q) hp[q] = ((const f32x2*)hbuf)[q];

        // prefetch P pair for t+1, char offset for t+2 (off critical path)
        f32x2 pn = *(const f32x2*)(Pb + poffn + lane8);
        int poff2 = chars[t + 2];

        // two dot products, 2 packed accumulator chains each
        f32x2 A0, A1, B0, B1;
        pkmul(A0, hp[0], wh0p[0]);
        pkmul(A1, hp[1], wh0p[1]);
        pkmul(B0, hp[0], wh1p[0]);
        pkmul(B1, hp[1], wh1p[1]);
        #pragma unroll
        for (int k = 2; k < 12; k += 2) {
            pkfma(A0, hp[k],     wh0p[k]);
            pkfma(A1, hp[k + 1], wh0p[k + 1]);
            pkfma(B0, hp[k],     wh1p[k]);
            pkfma(B1, hp[k + 1], wh1p[k + 1]);
        }
        pkfma(A0, hp[12], wh0p[12]);
        pkfma(B0, hp[12], wh1p[12]);
        f32x2 sa = A0 + A1;
        f32x2 sb = B0 + B1;
        const float a0s = sa.x + sa.y + pa.x;   // prescaled for exp2
        const float a1s = sb.x + sb.y + pa.y;

        // activations
        float y0 = __builtin_amdgcn_rcpf(1.0f + __builtin_amdgcn_exp2f(a0s));
        float y1 = fmaf(__builtin_amdgcn_rcpf(1.0f + __builtin_amdgcn_exp2f(a1s)),
                        s1, d1);
        float y1_2 = y1 + y1;

        // cross-lane: lanes 32..57 receive scaled i*g from lanes 0..25.
        // Proven semantics: sw[0][32+j] = vsrc_old[j]. vdst = y0 (live after
        // => distinct registers guaranteed), vsrc = pr.
        float pr = y0 * y1;                      // i * (-2log2e * tanh g) in lanes<26
        auto sw = __builtin_amdgcn_permlane32_swap(__float_as_int(y0),
                                                   __float_as_int(pr),
                                                   false, false);
        float rcv = __int_as_float(sw[0]);

        // C', h update (meaningful in lanes 32..57)
        C = fmaf(y0, C, rcv);                    // sig(f)*C' + (-2log2e)*i*g
        float rc = __builtin_amdgcn_rcpf(1.0f + __builtin_amdgcn_exp2f(C));
        float hv = fmaf(rc, y1_2, -y1);          // sig(o)*tanh(c)
        hbuf[hidx] = hv;

        pa = pn; poffn = poff2;
    }

    __syncthreads();

    // ---- final linear: out[b, j] = W_lin[j]·h + b_lin[j] ----
    if (l < H) {
        float acc = b_lin[l];
        #pragma unroll
        for (int k = 0; k < H; ++k)
            acc = fmaf(W_lin[l * H + k], hbuf[k], acc);
        out[(size_t)b * H + l] = acc;
    }
}

extern "C" void kernel_launch(void* const* d_in, const int* in_sizes, int n_in,
                              void* d_out, int out_size, void* d_ws, size_t ws_size,
                              hipStream_t stream) {
    const int*   x     = (const int*)d_in[0];
    const float* E     = (const float*)d_in[1];
    const float* W_ih  = (const float*)d_in[2];
    const float* W_hh  = (const float*)d_in[3];
    const float* b_ih  = (const float*)d_in[4];
    const float* b_hh  = (const float*)d_in[5];
    const float* W_lin = (const float*)d_in[6];
    const float* b_lin = (const float*)d_in[7];
    float* out = (float*)d_out;

    const int T = 1024;
    const int B = in_sizes[0] / T;   // 2048

    lstm_char_kernel<<<B, 64, 0, stream>>>(x, E, W_ih, W_hh, b_ih, b_hh,
                                           W_lin, b_lin, out, T);
}